// Round 4
// baseline (1057.507 us; speedup 1.0000x reference)
//
#include <hip/hip_runtime.h>

typedef __bf16 bf16x8 __attribute__((ext_vector_type(8)));
typedef __bf16 bf16x4 __attribute__((ext_vector_type(4)));
typedef float f32x4 __attribute__((ext_vector_type(4)));

__device__ __forceinline__ __bf16 f2bf(float f) {
  unsigned u = __builtin_bit_cast(unsigned, f);
  u += 0x7FFFu + ((u >> 16) & 1u);            // RNE round to bf16
  unsigned short s = (unsigned short)(u >> 16);
  return __builtin_bit_cast(__bf16, s);
}

// out = nodes (d_out is poisoned before every timed call)
__global__ void init_out(const float* __restrict__ nodes, float* __restrict__ out) {
  int i = blockIdx.x * blockDim.x + threadIdx.x;   // 1,600,000 float4s
  ((float4*)out)[i] = ((const float4*)nodes)[i];
}

// 256 thr (4 waves), 8 tiles x 16 edges per wave = 512 edges/block, 3125 blocks.
// LDS: w1a 32K + w2t 16K + hid 4x4K = 64 KB -> 2 blocks/CU (8 waves/CU).
// Register budget lesson (R2/R3): compiler gives 128 arch VGPRs here; keep the
// arch-side live set under that. NO w1c register cache. Accumulators -> AGPRs.
// Stage1 (transposed): hiddenT = W1^T X^T; A = W1 frags from LDS shared across
// dirs (dir1 = bx[kt^2]); B = X gathered from global, prefetched 1 tile ahead.
// Stage2: M = hidden W2; W2 B-frags shared across dirs. Scatter via atomicAdd.
__launch_bounds__(256, 2)
__global__ void edge_mlp(const float* __restrict__ nodes,
                         const int* __restrict__ edges,
                         const float* __restrict__ W1,
                         const float* __restrict__ b1,
                         const float* __restrict__ W2,
                         const float* __restrict__ b2,
                         float* __restrict__ out) {
  __shared__ __bf16 w1a[128 * 128];    // [u][k] 16B-xor-swizzled, 32 KB
  __shared__ __bf16 w2t[64 * 128];     // [n][k] swizzled, 16 KB
  __shared__ __bf16 hid[4][16 * 128];  // per-wave [edge][unit] swizzled, 16 KB

  const int tid = threadIdx.x;

  // ---- stage W1: thread owns (u, kblk-chunk): coalesced column reads, b128 writes
  {
    const int su = tid & 127, skh = tid >> 7;   // u, kblk-half
#pragma unroll
    for (int i = 0; i < 8; ++i) {
      int kb = skh * 8 + i;
      bf16x8 c;
#pragma unroll
      for (int j = 0; j < 8; ++j) c[j] = f2bf(W1[(kb * 8 + j) * 128 + su]);
      *(bf16x8*)&w1a[su * 128 + ((kb ^ (su & 15)) << 3)] = c;
    }
  }
  // ---- stage W2 likewise
  {
    const int su = tid & 63, skh = tid >> 6;
#pragma unroll
    for (int i = 0; i < 4; ++i) {
      int kb = skh * 4 + i;
      bf16x8 c;
#pragma unroll
      for (int j = 0; j < 8; ++j) c[j] = f2bf(W2[(kb * 8 + j) * 64 + su]);
      *(bf16x8*)&w2t[su * 128 + ((kb ^ (su & 15)) << 3)] = c;
    }
  }
  __syncthreads();

  const int lane = tid & 63;
  const int wave = tid >> 6;
  const int col = lane & 15;
  const int quad = lane >> 4;
  __bf16* myhid = hid[wave];
  const int2* edg = (const int2*)edges;
  const int ebase = blockIdx.x * 512 + wave * 128 + col;

  // biases cached once (b1r: 32 regs, indexed [ut], component r; unit = ut*16+quad*4+r)
  f32x4 b1r[8];
  {
    const float4* b1q = (const float4*)b1;
#pragma unroll
    for (int ut = 0; ut < 8; ++ut) {
      float4 bi = b1q[ut * 4 + quad];
      f32x4 b; b[0] = bi.x; b[1] = bi.y; b[2] = bi.z; b[3] = bi.w;
      b1r[ut] = b;
    }
  }
  float b2v[4];
#pragma unroll
  for (int nt = 0; nt < 4; ++nt) b2v[nt] = b2[nt * 16 + col];

  // ---- software pipeline: edges 2 ahead, node gather 1 ahead ----
  int2 ep0 = edg[ebase];            // tile 0 endpoints
  int2 ep1 = edg[ebase + 16];       // tile 1 endpoints
  float4 raw[8];
  {
    const float* pi = nodes + (size_t)ep0.x * 64 + quad * 8;
    const float* pj = nodes + (size_t)ep0.y * 64 + quad * 8;
#pragma unroll
    for (int kt = 0; kt < 4; ++kt) {
      const float* src = (kt < 2) ? pi + kt * 32 : pj + (kt - 2) * 32;
      raw[kt * 2] = ((const float4*)src)[0];
      raw[kt * 2 + 1] = ((const float4*)src)[1];
    }
  }

  for (int t = 0; t < 8; ++t) {
    // current tile's B-frags from prefetched raw (raw dead after this)
    bf16x8 bx[4];
#pragma unroll
    for (int kt = 0; kt < 4; ++kt) {
      float4 v0 = raw[kt * 2], v1 = raw[kt * 2 + 1];
      bf16x8 a;
      a[0] = f2bf(v0.x); a[1] = f2bf(v0.y); a[2] = f2bf(v0.z); a[3] = f2bf(v0.w);
      a[4] = f2bf(v1.x); a[5] = f2bf(v1.y); a[6] = f2bf(v1.z); a[7] = f2bf(v1.w);
      bx[kt] = a;
    }
    const int ie = ep0.x, je = ep0.y;

    // issue next tile's gather now (latency hidden behind this tile's compute)
    if (t < 7) {
      const float* pi = nodes + (size_t)ep1.x * 64 + quad * 8;
      const float* pj = nodes + (size_t)ep1.y * 64 + quad * 8;
#pragma unroll
      for (int kt = 0; kt < 4; ++kt) {
        const float* src = (kt < 2) ? pi + kt * 32 : pj + (kt - 2) * 32;
        raw[kt * 2] = ((const float4*)src)[0];
        raw[kt * 2 + 1] = ((const float4*)src)[1];
      }
      ep0 = ep1;
      int tn = (t + 2 < 8) ? (t + 2) : 7;     // clamp (redundant reload ok)
      ep1 = edg[ebase + tn * 16];
    }

    // ---- stage 1 (both dirs, shared W1 A-frags from LDS): acc init = b1 ----
    f32x4 acc0[8], acc1[8];
#pragma unroll
    for (int ut = 0; ut < 8; ++ut) { acc0[ut] = b1r[ut]; acc1[ut] = b1r[ut]; }
#pragma unroll
    for (int kt = 0; kt < 4; ++kt) {
      const int kb = kt * 4 + quad;
#pragma unroll
      for (int ut = 0; ut < 8; ++ut) {
        const bf16x8 a = *(const bf16x8*)&w1a[(ut * 16 + col) * 128 + ((kb ^ col) << 3)];
        acc0[ut] = __builtin_amdgcn_mfma_f32_16x16x32_bf16(a, bx[kt], acc0[ut], 0, 0, 0);
        acc1[ut] = __builtin_amdgcn_mfma_f32_16x16x32_bf16(a, bx[kt ^ 2], acc1[ut], 0, 0, 0);
      }
    }

    // ---- relu + hid round-trips (dir0 then dir1), A-frags into regs ----
    bf16x8 ah0[4], ah1[4];
#pragma unroll
    for (int ut = 0; ut < 8; ++ut) {          // dir0: 4 units/lane = b64 write
      bf16x4 h;
#pragma unroll
      for (int r = 0; r < 4; ++r) {
        float x = acc0[ut][r];
        h[r] = f2bf(x > 0.0f ? x : 0.0f);
      }
      int blk = ut * 2 + (quad >> 1);
      *(bf16x4*)&myhid[col * 128 + ((blk ^ col) << 3) + ((quad & 1) << 2)] = h;
    }
#pragma unroll
    for (int kt = 0; kt < 4; ++kt)
      ah0[kt] = *(const bf16x8*)&myhid[col * 128 + (((kt * 4 + quad) ^ col) << 3)];
#pragma unroll
    for (int ut = 0; ut < 8; ++ut) {          // dir1
      bf16x4 h;
#pragma unroll
      for (int r = 0; r < 4; ++r) {
        float x = acc1[ut][r];
        h[r] = f2bf(x > 0.0f ? x : 0.0f);
      }
      int blk = ut * 2 + (quad >> 1);
      *(bf16x4*)&myhid[col * 128 + ((blk ^ col) << 3) + ((quad & 1) << 2)] = h;
    }
#pragma unroll
    for (int kt = 0; kt < 4; ++kt)
      ah1[kt] = *(const bf16x8*)&myhid[col * 128 + (((kt * 4 + quad) ^ col) << 3)];

    // ---- stage 2 (both dirs, shared W2 B-frags) ----
    f32x4 m0[4], m1[4];
#pragma unroll
    for (int nt = 0; nt < 4; ++nt) { m0[nt] = (f32x4)0.0f; m1[nt] = (f32x4)0.0f; }
#pragma unroll
    for (int kt = 0; kt < 4; ++kt) {
      const int kb = kt * 4 + quad;
#pragma unroll
      for (int nt = 0; nt < 4; ++nt) {
        const bf16x8 wf = *(const bf16x8*)&w2t[(nt * 16 + col) * 128 + ((kb ^ col) << 3)];
        m0[nt] = __builtin_amdgcn_mfma_f32_16x16x32_bf16(ah0[kt], wf, m0[nt], 0, 0, 0);
        m1[nt] = __builtin_amdgcn_mfma_f32_16x16x32_bf16(ah1[kt], wf, m1[nt], 0, 0, 0);
      }
    }

    // ---- scatter: C col = n (lane&15), row = edge-in-tile = quad*4+r ----
#pragma unroll
    for (int r = 0; r < 4; ++r) {
      int row = quad * 4 + r;
      int ni = __shfl(ie, row, 64);
      int nj = __shfl(je, row, 64);
      float* di = out + (size_t)ni * 64;
      float* dj = out + (size_t)nj * 64;
#pragma unroll
      for (int nt = 0; nt < 4; ++nt) {
        atomicAdd(di + nt * 16 + col, m0[nt][r] + b2v[nt]);
        atomicAdd(dj + nt * 16 + col, m1[nt][r] + b2v[nt]);
      }
    }
  }
}

extern "C" void kernel_launch(void* const* d_in, const int* in_sizes, int n_in,
                              void* d_out, int out_size, void* d_ws, size_t ws_size,
                              hipStream_t stream) {
  const float* nodes = (const float*)d_in[0];
  const int*   edges = (const int*)d_in[1];
  const float* W1    = (const float*)d_in[2];
  const float* b1    = (const float*)d_in[3];
  const float* W2    = (const float*)d_in[4];
  const float* b2    = (const float*)d_in[5];
  float* out = (float*)d_out;

  init_out<<<6250, 256, 0, stream>>>(nodes, out);
  // 1,600,000 edges = 3125 blocks * (4 waves * 8 tiles * 16 edges)
  edge_mlp<<<3125, 256, 0, stream>>>(nodes, edges, W1, b1, W2, b2, out);
}

// Round 6
// 1018.489 us; speedup vs baseline: 1.0383x; 1.0383x over previous
//
#include <hip/hip_runtime.h>

typedef __bf16 bf16x8 __attribute__((ext_vector_type(8)));
typedef __bf16 bf16x4 __attribute__((ext_vector_type(4)));
typedef float f32x4 __attribute__((ext_vector_type(4)));

__device__ __forceinline__ __bf16 f2bf(float f) { return (__bf16)f; }  // RNE cast

// out = nodes (d_out is poisoned before every timed call)
__global__ void init_out(const float* __restrict__ nodes, float* __restrict__ out) {
  int i = blockIdx.x * blockDim.x + threadIdx.x;   // 1,600,000 float4s
  ((float4*)out)[i] = ((const float4*)nodes)[i];
}

// 256 thr (4 waves), 8 tiles x 16 edges per wave, 3125 blocks.
// LDS: w1a 32K + w2t 16K + hkt 4x1K + b1s 0.5K = 52.5 KB -> 3 blocks/CU.
// Correctness lesson (R5): the hid LDS round-trip write/read MUST be volatile —
// type-punned bf16x4-write/bf16x8-read let the compiler reorder dir1 writes
// before dir0 reads. volatile + per-wave in-order DS pipe = safe, no fences.
// Register lesson (R2-R4): no long-lived arch arrays (no raw prefetch, b1 from
// LDS per tile). Peak arch ~80; accs in AGPRs.
__launch_bounds__(256, 3)
__global__ void edge_mlp(const float* __restrict__ nodes,
                         const int* __restrict__ edges,
                         const float* __restrict__ W1,
                         const float* __restrict__ b1,
                         const float* __restrict__ W2,
                         const float* __restrict__ b2,
                         float* __restrict__ out) {
  __shared__ __bf16 w1a[128 * 128];   // [u][k] 16B-xor-swizzled, 32 KB
  __shared__ __bf16 w2t[64 * 128];    // [n][k] swizzled, 16 KB
  __shared__ __bf16 hkt[4][16 * 32];  // per-wave k-slice buffer, 1 KB each
  __shared__ float b1s[128];

  const int tid = threadIdx.x;

  // ---- stage W1: thread owns (u, kblk-chunk): coalesced column reads, b128 writes
  {
    const int su = tid & 127, skh = tid >> 7;   // u, kblk-half
#pragma unroll
    for (int i = 0; i < 8; ++i) {
      int kb = skh * 8 + i;
      bf16x8 c;
#pragma unroll
      for (int j = 0; j < 8; ++j) c[j] = f2bf(W1[(kb * 8 + j) * 128 + su]);
      *(bf16x8*)&w1a[su * 128 + ((kb ^ (su & 15)) << 3)] = c;
    }
  }
  // ---- stage W2 likewise
  {
    const int su = tid & 63, skh = tid >> 6;
#pragma unroll
    for (int i = 0; i < 4; ++i) {
      int kb = skh * 4 + i;
      bf16x8 c;
#pragma unroll
      for (int j = 0; j < 8; ++j) c[j] = f2bf(W2[(kb * 8 + j) * 64 + su]);
      *(bf16x8*)&w2t[su * 128 + ((kb ^ (su & 15)) << 3)] = c;
    }
  }
  if (tid < 32) ((float4*)b1s)[tid] = ((const float4*)b1)[tid];
  __syncthreads();

  const int lane = tid & 63;
  const int wave = tid >> 6;
  const int col = lane & 15;
  const int quad = lane >> 4;
  volatile __bf16* myh = hkt[wave];
  const int2* edg = (const int2*)edges;
  const int ebase = blockIdx.x * 512 + wave * 128 + col;

  float b2v[4];
#pragma unroll
  for (int nt = 0; nt < 4; ++nt) b2v[nt] = b2[nt * 16 + col];

  int2 cur = edg[ebase];
  for (int t = 0; t < 8; ++t) {
    const int2 nxt = (t < 7) ? edg[ebase + (t + 1) * 16] : cur;

    // gather X = concat(h_i, h_j): lane edge=col, k = kt*32 + quad*8 + j
    bf16x8 bx[4];
    {
      const float* pi = nodes + (size_t)cur.x * 64 + quad * 8;
      const float* pj = nodes + (size_t)cur.y * 64 + quad * 8;
#pragma unroll
      for (int kt = 0; kt < 4; ++kt) {
        const float* src = (kt < 2) ? pi + kt * 32 : pj + (kt - 2) * 32;
        float4 v0 = ((const float4*)src)[0];
        float4 v1 = ((const float4*)src)[1];
        bf16x8 a;
        a[0] = f2bf(v0.x); a[1] = f2bf(v0.y); a[2] = f2bf(v0.z); a[3] = f2bf(v0.w);
        a[4] = f2bf(v1.x); a[5] = f2bf(v1.y); a[6] = f2bf(v1.z); a[7] = f2bf(v1.w);
        bx[kt] = a;
      }
    }
    const int ie = cur.x, je = cur.y;
    cur = nxt;

    // ---- stage 1 (both dirs share W1 A-frags; dir1 = bx[kt^2]); acc init = b1 (LDS)
    f32x4 acc0[8], acc1[8];
#pragma unroll
    for (int ut = 0; ut < 8; ++ut) {
      f32x4 bi = *(const f32x4*)&b1s[(ut * 4 + quad) * 4];  // broadcast read
      acc0[ut] = bi; acc1[ut] = bi;
    }
#pragma unroll
    for (int kt = 0; kt < 4; ++kt) {
      const int kb = kt * 4 + quad;
#pragma unroll
      for (int ut = 0; ut < 8; ++ut) {
        const bf16x8 a = *(const bf16x8*)&w1a[(ut * 16 + col) * 128 + ((kb ^ col) << 3)];
        acc0[ut] = __builtin_amdgcn_mfma_f32_16x16x32_bf16(a, bx[kt], acc0[ut], 0, 0, 0);
        acc1[ut] = __builtin_amdgcn_mfma_f32_16x16x32_bf16(a, bx[kt ^ 2], acc1[ut], 0, 0, 0);
      }
    }

    // ---- stage 2, per dir; per-kt LDS round-trip through the 1 KB buffer ----
#pragma unroll
    for (int dir = 0; dir < 2; ++dir) {
      const f32x4* acc = dir ? acc1 : acc0;
      f32x4 m[4];
#pragma unroll
      for (int nt = 0; nt < 4; ++nt) m[nt] = (f32x4)0.0f;

#pragma unroll
      for (int kt = 0; kt < 4; ++kt) {
        // relu+pack acc[kt*2+s] -> local units s*16+quad*4+r of edge col
#pragma unroll
        for (int s = 0; s < 2; ++s) {
          f32x4 a = acc[kt * 2 + s];
          bf16x4 h;
#pragma unroll
          for (int r = 0; r < 4; ++r) {
            float x = a[r];
            h[r] = f2bf(x > 0.0f ? x : 0.0f);
          }
          int bl = s * 2 + (quad >> 1);  // 16B block in 64B row, xor-swizzled
          *(volatile bf16x4*)(myh + col * 32 + ((bl ^ (col & 3)) << 3) +
                              ((quad & 1) << 2)) = h;
        }
        // read A-frag: local units quad*8..quad*8+7 (block quad, swizzled)
        bf16x4 lo = *(volatile bf16x4*)(myh + col * 32 + ((quad ^ (col & 3)) << 3));
        bf16x4 hi = *(volatile bf16x4*)(myh + col * 32 + ((quad ^ (col & 3)) << 3) + 4);
        bf16x8 ah;
#pragma unroll
        for (int i = 0; i < 4; ++i) { ah[i] = lo[i]; ah[4 + i] = hi[i]; }

        const int kb = kt * 4 + quad;
#pragma unroll
        for (int nt = 0; nt < 4; ++nt) {
          const bf16x8 wf = *(const bf16x8*)&w2t[(nt * 16 + col) * 128 + ((kb ^ col) << 3)];
          m[nt] = __builtin_amdgcn_mfma_f32_16x16x32_bf16(ah, wf, m[nt], 0, 0, 0);
        }
      }

      // scatter: C col = n (lane&15), row = edge-in-tile = quad*4+r
      const int srcn = dir ? je : ie;
#pragma unroll
      for (int r = 0; r < 4; ++r) {
        int row = quad * 4 + r;
        int node = __shfl(srcn, row, 64);
        float* dst = out + (size_t)node * 64;
#pragma unroll
        for (int nt = 0; nt < 4; ++nt) {
          atomicAdd(dst + nt * 16 + col, m[nt][r] + b2v[nt]);
        }
      }
    }
  }
}

extern "C" void kernel_launch(void* const* d_in, const int* in_sizes, int n_in,
                              void* d_out, int out_size, void* d_ws, size_t ws_size,
                              hipStream_t stream) {
  const float* nodes = (const float*)d_in[0];
  const int*   edges = (const int*)d_in[1];
  const float* W1    = (const float*)d_in[2];
  const float* b1    = (const float*)d_in[3];
  const float* W2    = (const float*)d_in[4];
  const float* b2    = (const float*)d_in[5];
  float* out = (float*)d_out;

  init_out<<<6250, 256, 0, stream>>>(nodes, out);
  // 1,600,000 edges = 3125 blocks * (4 waves * 8 tiles * 16 edges)
  edge_mlp<<<3125, 256, 0, stream>>>(nodes, edges, W1, b1, W2, b2, out);
}